// Round 5
// baseline (89.027 us; speedup 1.0000x reference)
//
#include <hip/hip_runtime.h>
#include <hip/hip_bf16.h>

// out[b,u] = exp(-0.5 * (|x_b|^2 - 2*x.mu + |mu_u|^2))
// x: (65536, 64) f32; mu: (64, 256) f32; out: (65536, 256) f32.
// bf16 MFMA (16x16x32) cross term; |x|^2 / |mu|^2 in fp32 from originals.
// Round-5 change vs round 4 (88.2us): epilogue routed through wave-private
// LDS so global stores are contiguous dwordx4 (1KB/wave/instr, full lines)
// instead of 4-row-interleaved dwords (64B/row) -- targets write-allocate/RFO
// overhead (kernel ~24us matches 17+67+67MB traffic; full-line stores should
// drop the extra 67MB read). Also: first x-tile loads hoisted above mu setup.

typedef __attribute__((ext_vector_type(8))) short short8;   // 8 bf16 (4 VGPRs)
typedef __attribute__((ext_vector_type(4))) float floatx4;  // MFMA C/D frag

#define GRIDB 1024
#define TILES 4   // 1024 * 4 * 16 rows = 65536

__device__ inline short f2bf_rne(float f) {
    unsigned int u = __float_as_uint(f);
    u += 0x7fffu + ((u >> 16) & 1u);   // round-to-nearest-even (no NaN in data)
    return (short)(u >> 16);
}

__global__ __launch_bounds__(256, 4) void rbf_kernel(
    const float* __restrict__ x, const float* __restrict__ mu,
    float* __restrict__ out)
{
    const int tid  = threadIdx.x;
    const int wave = tid >> 6;       // 0..3, owns u in [64*wave, 64*wave+64)
    const int lane = tid & 63;
    const int l15  = lane & 15;
    const int g    = lane >> 4;      // 0..3
    const int ubase = wave * 64;

    __shared__ float sbuf[4][16 * 64];   // per-wave 16-row x 64-col staging (16KB)

    // ---- hoist first x-tile loads: in flight during the whole mu setup ----
    int rt = blockIdx.x;
    const float* xr0 = x + (size_t)(rt * 16 + l15) * 64 + 8 * g;
    floatx4 c0 = *(const floatx4*)(xr0);
    floatx4 c1 = *(const floatx4*)(xr0 + 4);
    floatx4 c2 = *(const floatx4*)(xr0 + 32);
    floatx4 c3 = *(const floatx4*)(xr0 + 36);

    // ---- B (mu) fragments: loaded once per block, register-resident ----
    // frag layout (16x16x32 bf16): lane holds B[k = 32h + 8g + e][u0 + l15]
    short8 bfrag[4][2];
    float  msq[4];                   // -0.5 * |mu_u|^2 for col of tile t
    #pragma unroll
    for (int t = 0; t < 4; ++t) {
        const int u = ubase + t * 16 + l15;
        float sq = 0.f;
        #pragma unroll
        for (int h = 0; h < 2; ++h) {
            short8 bf;
            const int k0 = 32 * h + 8 * g;
            #pragma unroll
            for (int e = 0; e < 8; ++e) {
                float v = mu[(k0 + e) * 256 + u];
                sq += v * v;
                bf[e] = f2bf_rne(v);
            }
            bfrag[t][h] = bf;
        }
        sq += __shfl_xor(sq, 16);
        sq += __shfl_xor(sq, 32);
        msq[t] = -0.5f * sq;
    }

    // ---- 4 row-tiles per block, 2-deep pipelined x loads ----
    #pragma unroll
    for (int i = 0; i < TILES; ++i) {
        floatx4 n0, n1, n2, n3;
        if (i + 1 < TILES) {
            const float* xn = x + (size_t)((rt + GRIDB) * 16 + l15) * 64 + 8 * g;
            n0 = *(const floatx4*)(xn);
            n1 = *(const floatx4*)(xn + 4);
            n2 = *(const floatx4*)(xn + 32);
            n3 = *(const floatx4*)(xn + 36);
        }

        // A frag: lane holds x[b0 + l15][k = 32h + 8g + e]; fp32 |x|^2 alongside
        short8 a0, a1;
        float xsq = 0.f;
        #pragma unroll
        for (int e = 0; e < 4; ++e) {
            xsq += c0[e] * c0[e] + c1[e] * c1[e];
            xsq += c2[e] * c2[e] + c3[e] * c3[e];
            a0[e]     = f2bf_rne(c0[e]);
            a0[e + 4] = f2bf_rne(c1[e]);
            a1[e]     = f2bf_rne(c2[e]);
            a1[e + 4] = f2bf_rne(c3[e]);
        }
        xsq += __shfl_xor(xsq, 16);
        xsq += __shfl_xor(xsq, 32);
        float xh[4];
        #pragma unroll
        for (int r = 0; r < 4; ++r)
            xh[r] = -0.5f * __shfl(xsq, 4 * g + r);   // row b0 + 4g + r

        const int b0 = rt * 16;
        // compute + exp into wave-private LDS tile (row-major 16x64)
        #pragma unroll
        for (int t = 0; t < 4; ++t) {
            floatx4 acc = {0.f, 0.f, 0.f, 0.f};
            acc = __builtin_amdgcn_mfma_f32_16x16x32_bf16(a0, bfrag[t][0], acc, 0, 0, 0);
            acc = __builtin_amdgcn_mfma_f32_16x16x32_bf16(a1, bfrag[t][1], acc, 0, 0, 0);
            #pragma unroll
            for (int r = 0; r < 4; ++r) {
                float arg = acc[r] + xh[r] + msq[t];
                sbuf[wave][(4 * g + r) * 64 + t * 16 + l15] = __expf(arg);
            }
        }
        // contiguous full-line stores: 4 x dwordx4/lane = 1KB/wave/instr
        #pragma unroll
        for (int s = 0; s < 4; ++s) {
            const int f = s * 256 + lane * 4;         // float idx in 16x64 tile
            const int row = f >> 6, col = f & 63;
            floatx4 v = *(const floatx4*)&sbuf[wave][f];
            *(floatx4*)&out[(size_t)(b0 + row) * 256 + ubase + col] = v;
        }

        if (i + 1 < TILES) {
            c0 = n0; c1 = n1; c2 = n2; c3 = n3;
            rt += GRIDB;
        }
    }
}

extern "C" void kernel_launch(void* const* d_in, const int* in_sizes, int n_in,
                              void* d_out, int out_size, void* d_ws, size_t ws_size,
                              hipStream_t stream) {
    const float* x  = (const float*)d_in[0];   // (65536, 64)
    const float* mu = (const float*)d_in[1];   // (64, 256)
    float* out = (float*)d_out;                // (65536, 256)
    hipLaunchKernelGGL(rbf_kernel, dim3(GRIDB), dim3(256), 0, stream, x, mu, out);
}